// Round 1
// baseline (8670.977 us; speedup 1.0000x reference)
//
#include <hip/hip_runtime.h>
#include <hip/hip_bf16.h>

#define SEQ   512
#define BATCH 64
#define INF   512
#define H     1024
#define G4H   4096

typedef short  short8  __attribute__((ext_vector_type(8)));
typedef float  float4v __attribute__((ext_vector_type(4)));

// ---------------- conversion / init kernels ----------------

__global__ void f32_to_bf16_k(const float* __restrict__ src,
                              __hip_bfloat16* __restrict__ dst, int n) {
    int i = blockIdx.x * blockDim.x + threadIdx.x;
    int stride = gridDim.x * blockDim.x;
    for (; i < n; i += stride) dst[i] = __float2bfloat16(src[i]);
}

__global__ void init_state_k(const float* __restrict__ h0, const float* __restrict__ c0,
                             __hip_bfloat16* __restrict__ hb, float* __restrict__ cb) {
    int i = blockIdx.x * blockDim.x + threadIdx.x;
    if (i < BATCH * H) { hb[i] = __float2bfloat16(h0[i]); cb[i] = c0[i]; }
}

// ---------------- per-timestep fused gate GEMM + LSTM cell update ----------------
// grid: 64 blocks (one per 16-wide hidden slice j0), block: 512 threads = 8 waves.
// wave w: gate g = w&3, M-half mh = w>>2 (two 16-row batch tiles each).
// gates[b][g*H + j0+j] = sum_k [x_t | h] [b][k] * [W_ih | W_hh][row][k]   (K = 1536)

__global__ __launch_bounds__(512)
void lstm_step(const __hip_bfloat16* __restrict__ xb,   // [SEQ][B][INF] bf16
               const __hip_bfloat16* __restrict__ Wih,  // [4096][512]  bf16
               const __hip_bfloat16* __restrict__ Whh,  // [4096][1024] bf16
               const float* __restrict__ bias,          // [4096] f32
               const __hip_bfloat16* __restrict__ hprev,// [B][H] bf16
               __hip_bfloat16* __restrict__ hnext,      // [B][H] bf16
               float* __restrict__ cbuf,                // [B][H] f32 (in/out)
               float* __restrict__ hseq_out,            // d_out base (h_seq region)
               int t)
{
    // A staging: 64 rows x 128 k, padded to 136 (row stride 272B -> 2-way bank alias, free)
    __shared__ __align__(16) __hip_bfloat16 As[64 * 136];
    __shared__ float Gs[4][64][16];   // gate exchange: [gate][batch][j]

    const int tid  = threadIdx.x;
    const int lane = tid & 63;
    const int wave = tid >> 6;        // 0..7
    const int g    = wave & 3;        // gate
    const int mh   = wave >> 2;       // 0..1  (batch half)
    const int j0   = blockIdx.x * 16;

    const int ln15 = lane & 15;
    const int kgrp = lane >> 4;       // 0..3

    float4v acc0 = {0.f, 0.f, 0.f, 0.f};
    float4v acc1 = {0.f, 0.f, 0.f, 0.f};

    const int rW = g * H + j0 + ln15;     // weight row for this lane's B-frag (n = lane&15)

    for (int kc = 0; kc < 12; ++kc) {     // 12 chunks of K=128 (4 from x, 8 from h)
        __syncthreads();
        // cooperative stage: 64x128 bf16 = 1024 16B units, 2 per thread
        #pragma unroll
        for (int r = 0; r < 2; ++r) {
            int u    = r * 512 + tid;
            int row  = u >> 4;
            int c16  = u & 15;
            const __hip_bfloat16* src;
            if (kc < 4) src = xb + (size_t)t * BATCH * INF + row * INF + kc * 128 + c16 * 8;
            else        src = hprev + row * H + (kc - 4) * 128 + c16 * 8;
            short8 v = *(const short8*)src;
            *(short8*)&As[row * 136 + c16 * 8] = v;
        }
        __syncthreads();
        #pragma unroll
        for (int ks = 0; ks < 4; ++ks) {  // 4 k-steps of 32 per chunk
            int kk = kc * 128 + ks * 32;
            const __hip_bfloat16* wsrc;
            if (kc < 4) wsrc = Wih + (size_t)rW * INF + kk + kgrp * 8;
            else        wsrc = Whh + (size_t)rW * H + (kk - 512) + kgrp * 8;
            short8 bfrag = *(const short8*)wsrc;
            int colb = ks * 32 + kgrp * 8;
            short8 afrag0 = *(const short8*)&As[(mh * 32 + ln15) * 136 + colb];
            acc0 = __builtin_amdgcn_mfma_f32_16x16x32_bf16(afrag0, bfrag, acc0, 0, 0, 0);
            short8 afrag1 = *(const short8*)&As[(mh * 32 + 16 + ln15) * 136 + colb];
            acc1 = __builtin_amdgcn_mfma_f32_16x16x32_bf16(afrag1, bfrag, acc1, 0, 0, 0);
        }
    }
    __syncthreads();
    // C/D layout (m89-verified): col = lane&15, row = (lane>>4)*4 + reg
    #pragma unroll
    for (int r = 0; r < 4; ++r) {
        int brow = mh * 32 + kgrp * 4 + r;
        Gs[g][brow][ln15]      = acc0[r];
        Gs[g][brow + 16][ln15] = acc1[r];
    }
    __syncthreads();
    // elementwise cell update: 1024 (b,j) pairs over 512 threads
    #pragma unroll
    for (int p = 0; p < 2; ++p) {
        int idx = p * 512 + tid;
        int b   = idx >> 4;
        int j   = idx & 15;
        int jj  = j0 + j;
        float xi = Gs[0][b][j] + bias[0 * H + jj];
        float xf = Gs[1][b][j] + bias[1 * H + jj];
        float xg = Gs[2][b][j] + bias[2 * H + jj];
        float xo = Gs[3][b][j] + bias[3 * H + jj];
        float ig = 1.f / (1.f + __expf(-xi));
        float fg = 1.f / (1.f + __expf(-xf));
        float gg = 2.f / (1.f + __expf(-2.f * xg)) - 1.f;
        float og = 1.f / (1.f + __expf(-xo));
        int cidx = b * H + jj;
        float c  = cbuf[cidx];
        c = fg * c + ig * gg;
        cbuf[cidx] = c;
        float th = 2.f / (1.f + __expf(-2.f * c)) - 1.f;
        float h  = og * th;
        hseq_out[(size_t)t * BATCH * H + cidx] = h;
        hnext[cidx] = __float2bfloat16(h);
    }
}

// ---------------- tail: hT = h_seq[last], cT = c ----------------

__global__ void tail_copy_k(const float* __restrict__ cbuf, float* __restrict__ out) {
    int i = blockIdx.x * blockDim.x + threadIdx.x;
    if (i < BATCH * H) {
        out[(size_t)SEQ * BATCH * H + i]             = out[(size_t)(SEQ - 1) * BATCH * H + i];
        out[(size_t)SEQ * BATCH * H + BATCH * H + i] = cbuf[i];
    }
}

// ---------------- launch ----------------

extern "C" void kernel_launch(void* const* d_in, const int* in_sizes, int n_in,
                              void* d_out, int out_size, void* d_ws, size_t ws_size,
                              hipStream_t stream)
{
    const float* x    = (const float*)d_in[0];
    const float* Wih  = (const float*)d_in[1];
    const float* Whh  = (const float*)d_in[2];
    const float* bias = (const float*)d_in[3];
    const float* h0   = (const float*)d_in[4];
    const float* c0   = (const float*)d_in[5];
    float* out = (float*)d_out;

    // workspace layout (bytes): all offsets 16B-aligned; total ~44.6 MB
    char* ws = (char*)d_ws;
    __hip_bfloat16* xb   = (__hip_bfloat16*)(ws);             // 16,777,216 el -> 33,554,432 B
    __hip_bfloat16* Wihb = (__hip_bfloat16*)(ws + 33554432);  //  2,097,152 el ->  4,194,304 B
    __hip_bfloat16* Whhb = (__hip_bfloat16*)(ws + 37748736);  //  4,194,304 el ->  8,388,608 B
    __hip_bfloat16* hb   = (__hip_bfloat16*)(ws + 46137344);  //  2 x 65,536 el -> 262,144 B
    float*          cb   = (float*)(ws + 46399488);           //  65,536 f32  -> 262,144 B

    f32_to_bf16_k<<<2048, 256, 0, stream>>>(x,   xb,   SEQ * BATCH * INF);
    f32_to_bf16_k<<<512,  256, 0, stream>>>(Wih, Wihb, G4H * INF);
    f32_to_bf16_k<<<1024, 256, 0, stream>>>(Whh, Whhb, G4H * H);
    init_state_k<<<256, 256, 0, stream>>>(h0, c0, hb, cb);

    for (int t = 0; t < SEQ; ++t) {
        const __hip_bfloat16* hp = hb + (size_t)(t & 1) * (BATCH * H);
        __hip_bfloat16*       hn = hb + (size_t)((t + 1) & 1) * (BATCH * H);
        lstm_step<<<64, 512, 0, stream>>>(xb, Wihb, Whhb, bias, hp, hn, cb, out, t);
    }
    tail_copy_k<<<256, 256, 0, stream>>>(cb, out);
}